// Round 7
// baseline (842.251 us; speedup 1.0000x reference)
//
#include <hip/hip_runtime.h>
#include <hip/hip_bf16.h>

// GIN_34789235098229 — round 17: weight-stationary register MLP (zero LDS).
// Round 16 = 775 us; mlp 68.5us: occ 16%, VALU 35%, hbm 10% — LDS-pipe bound:
// per k-step 4x ds_read_b128 (48cyc) feeds only 16 FMAs (32cyc), plus bpermute,
// plus 32KB weight staging x1563 blocks. Fix: lane j holds W1/W2 columns j in
// 128 VGPRs (loaded once per wave); one wave does the full MLP for 32 nodes
// (8 batches of 4); activation broadcast via __builtin_amdgcn_readlane
// (VALU/SGPR path, per-SIMD, literal lanes after unroll — cannot fall back to
// the shared LDS bpermute pipe). FMA order per output is ascending k ==
// bit-identical mlp outputs to rounds 10-16. Stats: lane==feature, so per-wave
// partials are plain stores, no butterfly. Grid 782 blocks = 3128 waves
// (~3 waves/SIMD at ~160 VGPR, all resident). NWAVE 6252->3128.
// Everything else unchanged from round 16.

typedef unsigned short ushort_t;
typedef unsigned int uint_t;

#define NN 100000
#define EE 3200000
#define GG 512
#define NBK 391    // ceil(NN/256); bucket = node >> 8
#define NHB 256    // histogram blocks
#define ECHUNK 12500  // EE / NHB exactly
#define MLPBLOCKS 782        // ceil(100000 / 32 nodes-per-wave / 4 waves-per-block)
#define NWAVE (MLPBLOCKS * 4)  // 3128 wave slots for stats partials

// ---------- detection ----------
__global__ __launch_bounds__(256) void detect_kernel(
    const uint_t* __restrict__ xw, const uint_t* __restrict__ ew,
    const uint_t* __restrict__ bw, int* __restrict__ flags)
{
    __shared__ int sb[256], se[256], sbb[256];
    int t = threadIdx.x;
    uint_t w = xw[t];
    uint_t eL = (w >> 7) & 0xffu;
    sb[t] = (eL >= 112u && eL <= 135u) ? 1 : 0;
    se[t] = (ew[2 * t + 1] == 0u) ? 1 : 0;
    sbb[t] = (bw[NN - 512 + 2 * t + 1] == 0u) ? 1 : 0;
    __syncthreads();
    for (int off = 128; off > 0; off >>= 1) {
        if (t < off) { sb[t] += sb[t + off]; se[t] += se[t + off]; sbb[t] += sbb[t + off]; }
        __syncthreads();
    }
    if (t == 0) {
        flags[0] = (sb[0] < 128) ? 1 : 0;   // 1 => fp32 floats
        flags[1] = (se[0] >= 128) ? 1 : 0;  // 1 => int64 edges
        flags[2] = (sbb[0] >= 128) ? 1 : 0; // 1 => int64 batch
    }
}

// ---------- canonicalization ----------
__global__ __launch_bounds__(256) void cvt_w_kernel(
    const void* __restrict__ W1, const void* __restrict__ b1,
    const void* __restrict__ W2, const void* __restrict__ b2,
    const void* __restrict__ g, const void* __restrict__ be,
    const int* __restrict__ flags, float* __restrict__ wf)
{
    int i = blockIdx.x * 256 + threadIdx.x;
    if (i >= 33792) return;
    const void* src; int off;
    if (i < 16384)      { src = W1; off = i; }
    else if (i < 32768) { src = W2; off = i - 16384; }
    else if (i < 33024) { src = b1; off = i - 32768; }
    else if (i < 33280) { src = b2; off = i - 33024; }
    else if (i < 33536) { src = g;  off = i - 33280; }
    else                { src = be; off = i - 33536; }
    float v = flags[0] ? ((const float*)src)[off]
                       : __bfloat162float(((const __hip_bfloat16*)src)[off]);
    wf[i] = v;
}

__global__ __launch_bounds__(256) void cvt_x_kernel(
    const void* __restrict__ x, const int* __restrict__ flags,
    float* __restrict__ zA, ushort_t* __restrict__ zb, int total)
{
    int i = blockIdx.x * 256 + threadIdx.x;
    if (i >= total) return;
    float v;
    ushort_t bits;
    if (flags[0]) {
        v = ((const float*)x)[i];
        __hip_bfloat16 b = __float2bfloat16(v);
        bits = *(ushort_t*)&b;
    } else {
        bits = ((const ushort_t*)x)[i];
        uint_t u = (uint_t)bits << 16;
        v = __uint_as_float(u);
    }
    zA[i] = v;
    zb[i] = bits;
}

// batch is SORTED: zero-atomic group offsets via boundary detection.
// gstart[g] (G+1 entries) = first index i with batch[i] >= g.
__global__ __launch_bounds__(256) void cvt_batch_kernel(
    const int* __restrict__ bw, const int* __restrict__ flags,
    int* __restrict__ b32, int* __restrict__ gstart, int n)
{
    int i = blockIdx.x * 256 + threadIdx.x;
    if (i >= n) return;
    int i64 = flags[2];
    int v = i64 ? bw[2 * i] : bw[i];
    b32[i] = v;
    int vn = (i + 1 < n) ? (i64 ? bw[2 * (i + 1)] : bw[i + 1]) : GG;
    if (i == 0) {
        for (int g = 0; g <= v; ++g) gstart[g] = 0;
    }
    if (vn != v) {
        for (int g = v + 1; g <= vn; ++g) gstart[g] = i + 1;
    }
}

// ---------- atomic-free CSR build (round 9, unchanged) ----------
__global__ __launch_bounds__(256) void count_hist_kernel(
    const int* __restrict__ ei, const int* __restrict__ flags,
    int* __restrict__ histo, int E)
{
    __shared__ int lh[NBK];
    int b = blockIdx.x, t = threadIdx.x;
    for (int j = t; j < NBK; j += 256) lh[j] = 0;
    __syncthreads();
    int i64 = flags[1];
    int e0 = b * ECHUNK, e1 = min(e0 + ECHUNK, E);
    for (int i = e0 + t; i < e1; i += 256) {
        int d = i64 ? ei[2 * (E + i)] : ei[E + i];
        atomicAdd(&lh[d >> 8], 1);
    }
    __syncthreads();
    for (int j = t; j < NBK; j += 256) histo[j * NHB + b] = lh[j];
}

__global__ __launch_bounds__(NHB) void blockscan_kernel(
    int* __restrict__ histo, int* __restrict__ tot)
{
    __shared__ int sd[NHB];
    int j = blockIdx.x, t = threadIdx.x;
    int v = histo[j * NHB + t];
    sd[t] = v;
    __syncthreads();
    #pragma unroll
    for (int off = 1; off < NHB; off <<= 1) {
        int add = (t >= off) ? sd[t - off] : 0;
        __syncthreads();
        sd[t] += add;
        __syncthreads();
    }
    histo[j * NHB + t] = sd[t] - v;
    if (t == NHB - 1) tot[j] = sd[NHB - 1];
}

__global__ __launch_bounds__(512) void bscan_kernel(
    const int* __restrict__ tot, int* __restrict__ bktoff)
{
    __shared__ int sd[512];
    int t = threadIdx.x;
    int v = (t < NBK) ? tot[t] : 0;
    sd[t] = v;
    __syncthreads();
    #pragma unroll
    for (int off = 1; off < 512; off <<= 1) {
        int add = (t >= off) ? sd[t - off] : 0;
        __syncthreads();
        sd[t] += add;
        __syncthreads();
    }
    if (t < NBK) bktoff[t] = sd[t] - v;
    if (t == 511) bktoff[NBK] = sd[511];
}

__global__ __launch_bounds__(256) void pair_scatter_kernel(
    const int* __restrict__ ei, const int* __restrict__ flags,
    const int* __restrict__ histo, const int* __restrict__ bktoff,
    int2* __restrict__ pairs, int E)
{
    __shared__ int cur[NBK];
    int b = blockIdx.x, t = threadIdx.x;
    for (int j = t; j < NBK; j += 256) cur[j] = histo[j * NHB + b] + bktoff[j];
    __syncthreads();
    int i64 = flags[1];
    int e0 = b * ECHUNK, e1 = min(e0 + ECHUNK, E);
    for (int i = e0 + t; i < e1; i += 256) {
        int d = i64 ? ei[2 * (E + i)] : ei[E + i];
        int s = i64 ? ei[2 * i]       : ei[i];
        int p = atomicAdd(&cur[d >> 8], 1);
        pairs[p] = make_int2(d, s);
    }
}

__global__ __launch_bounds__(256) void bucket_deg_kernel(
    const int2* __restrict__ pairs, const int* __restrict__ bktoff,
    int* __restrict__ deg, int N)
{
    __shared__ int cnt[256];
    int j = blockIdx.x, t = threadIdx.x;
    cnt[t] = 0;
    __syncthreads();
    int e0 = bktoff[j], e1 = bktoff[j + 1];
    for (int i = e0 + t; i < e1; i += 256)
        atomicAdd(&cnt[pairs[i].x & 255], 1);
    __syncthreads();
    int idx = j * 256 + t;
    if (idx < N) deg[idx] = cnt[t];
}

__global__ __launch_bounds__(256) void scan1_kernel(
    const int* __restrict__ deg, int* __restrict__ part, int* __restrict__ bsum, int n)
{
    __shared__ int sd[256];
    int t = threadIdx.x;
    int i0 = blockIdx.x * 1024 + t * 4;
    int v0 = 0, v1 = 0, v2 = 0, v3 = 0;
    if (i0 + 3 < n) {
        int4 v = *(const int4*)(deg + i0);
        v0 = v.x; v1 = v.y; v2 = v.z; v3 = v.w;
    } else if (i0 < n) {
        v0 = deg[i0];
        if (i0 + 1 < n) v1 = deg[i0 + 1];
        if (i0 + 2 < n) v2 = deg[i0 + 2];
    }
    int s = v0 + v1 + v2 + v3;
    sd[t] = s;
    __syncthreads();
    #pragma unroll
    for (int off = 1; off < 256; off <<= 1) {
        int add = (t >= off) ? sd[t - off] : 0;
        __syncthreads();
        sd[t] += add;
        __syncthreads();
    }
    int incl = sd[t];
    int e0 = incl - s;
    int p0 = e0 + v0, p1 = p0 + v1, p2 = p1 + v2, p3 = p2 + v3;
    if (i0 < n)     part[i0]     = p0;
    if (i0 + 1 < n) part[i0 + 1] = p1;
    if (i0 + 2 < n) part[i0 + 2] = p2;
    if (i0 + 3 < n) part[i0 + 3] = p3;
    if (t == 255) bsum[blockIdx.x] = incl;
}

__global__ __launch_bounds__(128) void scan2_kernel(int* __restrict__ bsum, int nb)
{
    __shared__ int sd[128];
    int t = threadIdx.x;
    int own = (t < nb) ? bsum[t] : 0;
    sd[t] = own;
    __syncthreads();
    #pragma unroll
    for (int off = 1; off < 128; off <<= 1) {
        int add = (t >= off) ? sd[t - off] : 0;
        __syncthreads();
        sd[t] += add;
        __syncthreads();
    }
    if (t < nb) bsum[t] = sd[t] - own;
}

__global__ __launch_bounds__(256) void scan3_kernel(
    const int* __restrict__ part, const int* __restrict__ bsum,
    const int* __restrict__ deg, int* __restrict__ indptr,
    float* __restrict__ inv_deg, int n)
{
    int i = blockIdx.x * 256 + threadIdx.x;
    if (i >= n) return;
    int val = part[i] + bsum[i >> 10];
    indptr[i + 1] = val;
    int d = deg[i];
    inv_deg[i] = (d > 0) ? 1.0f / (float)d : 0.0f;
    if (i == 0) indptr[0] = 0;
}

// invg from sorted-boundary gstart + identity-init of ac slot 0 (A=1, C=0)
__global__ __launch_bounds__(512) void invg_kernel(
    const int* __restrict__ gstart, float* __restrict__ invg,
    float* __restrict__ ac, int G)
{
    int g = threadIdx.x;
    if (g < G) {
        int c = gstart[g + 1] - gstart[g];
        invg[g] = (c > 0) ? 1.0f / (float)c : 0.0f;
    }
    if (g < 64) ac[g] = 1.0f;
    else if (g < 128) ac[g] = 0.0f;
}

__global__ __launch_bounds__(256) void csr_fill_kernel(
    const int2* __restrict__ pairs, const int* __restrict__ bktoff,
    const int* __restrict__ indptr, int* __restrict__ esrc, int N)
{
    __shared__ int cur[256];
    int j = blockIdx.x, t = threadIdx.x;
    int idx = j * 256 + t;
    cur[t] = (idx < N) ? indptr[idx] : 0;
    __syncthreads();
    int e0 = bktoff[j], e1 = bktoff[j + 1];
    for (int i = e0 + t; i < e1; i += 256) {
        int2 e = pairs[i];
        int p = atomicAdd(&cur[e.x & 255], 1);
        esrc[p] = e.y;
    }
}

// ---------- per-layer ----------
// agg: edge-index broadcast, explicit 16-deep gather batches (round-14 form).
// zout = A*(z_own + mean(z_nb)) + C*(1+[deg>0]); A,C from the ac slot.
__global__ __launch_bounds__(256) void agg_kernel(
    const float* __restrict__ zprev, const ushort_t* __restrict__ zb,
    const int* __restrict__ indptr, const int* __restrict__ esrc,
    const float* __restrict__ inv_deg, const float* __restrict__ ac,
    float* __restrict__ zout, int n)
{
    int t = threadIdx.x;
    int grp = t >> 4, l = t & 15;
    int lane = t & 63;
    int gl0 = lane & 48;
    int node = blockIdx.x * 16 + grp;
    if (node >= n) return;
    int e0 = indptr[node], e1 = indptr[node + 1];
    // hoisted independent loads: overlap with the gather loop
    float idg = inv_deg[node];
    float4 own = *(const float4*)(zprev + (size_t)node * 64 + l * 4);
    float4 A = *(const float4*)(ac + l * 4);
    float4 C = *(const float4*)(ac + 64 + l * 4);
    float a0 = 0.f, a1 = 0.f, a2 = 0.f, a3 = 0.f;
    const ushort_t* zbl = zb + l * 4;

    int base = e0;
    // full chunks: 16 gathers batched (issue loop separate from accumulate)
    for (; base + 16 <= e1; base += 16) {
        int myi = esrc[base + l];
        uint2 vv[16];
        #pragma unroll
        for (int j = 0; j < 16; ++j) {
            int s = __shfl(myi, gl0 + j, 64);
            vv[j] = *(const uint2*)(zbl + (size_t)s * 64);
        }
        #pragma unroll
        for (int j = 0; j < 16; ++j) {
            a0 += __uint_as_float(vv[j].x << 16);
            a1 += __uint_as_float(vv[j].x & 0xffff0000u);
            a2 += __uint_as_float(vv[j].y << 16);
            a3 += __uint_as_float(vv[j].y & 0xffff0000u);
        }
    }
    // remainder: masked 16-wide batch; pad lanes re-read edge-0's row (L1 hit)
    // and are forced to +0.0f => accumulation chain is bit-identical.
    int cnt = e1 - base;
    if (cnt > 0) {
        int myi = (l < cnt) ? esrc[base + l] : 0;
        uint2 vv[16];
        #pragma unroll
        for (int j = 0; j < 16; ++j) {
            int jj = (j < cnt) ? j : 0;
            int s = __shfl(myi, gl0 + jj, 64);
            uint2 v = *(const uint2*)(zbl + (size_t)s * 64);
            vv[j].x = (j < cnt) ? v.x : 0u;
            vv[j].y = (j < cnt) ? v.y : 0u;
        }
        #pragma unroll
        for (int j = 0; j < 16; ++j) {
            a0 += __uint_as_float(vv[j].x << 16);
            a1 += __uint_as_float(vv[j].x & 0xffff0000u);
            a2 += __uint_as_float(vv[j].y << 16);
            a3 += __uint_as_float(vv[j].y & 0xffff0000u);
        }
    }

    float cf = (idg > 0.f) ? 2.f : 1.f;
    float4 r;
    r.x = fmaf(A.x, fmaf(idg, a0, own.x), C.x * cf);
    r.y = fmaf(A.y, fmaf(idg, a1, own.y), C.y * cf);
    r.z = fmaf(A.z, fmaf(idg, a2, own.z), C.z * cf);
    r.w = fmaf(A.w, fmaf(idg, a3, own.w), C.w * cf);
    *(float4*)(zout + (size_t)node * 64 + l * 4) = r;
}

// MLP round 17: weight-stationary registers, lane == output feature.
// One wave = full MLP for 32 nodes (8 batches of 4). Broadcast via readlane.
// FMA order: ascending k per output == bit-identical to previous rounds.
#define RL(x, k) __uint_as_float(__builtin_amdgcn_readlane(__float_as_uint(x), (k)))
__global__ __launch_bounds__(256) void mlp_kernel(
    float* __restrict__ zf, ushort_t* __restrict__ zb,
    const float* __restrict__ W1f, const float* __restrict__ b1f,
    const float* __restrict__ W2f, const float* __restrict__ b2f,
    float* __restrict__ partials, int n)
{
    int t = threadIdx.x;
    int lane = t & 63;
    int w = (blockIdx.x * 256 + t) >> 6;   // global wave id, 0..NWAVE-1

    // weight columns in registers: w1k[k] = W1[k][lane] (coalesced loads)
    float w1k[64], w2k[64];
    #pragma unroll
    for (int k = 0; k < 64; ++k) {
        w1k[k] = W1f[k * 64 + lane];
        w2k[k] = W2f[k * 64 + lane];
    }
    float bias1 = b1f[lane];
    float bias2 = b2f[lane];
    float ssum = 0.f, ssq = 0.f;

    int n0 = w * 32;
    #pragma unroll 1
    for (int b = 0; b < 8; ++b) {
        int nb = n0 + b * 4;
        // wave-uniform validity (no divergence; invalid batches feed zeros)
        bool v0 = (nb < n), v1 = (nb + 1 < n), v2 = (nb + 2 < n), v3 = (nb + 3 < n);
        size_t r0 = (size_t)nb * 64 + lane;
        float z0 = v0 ? zf[r0]       : 0.f;
        float z1 = v1 ? zf[r0 + 64]  : 0.f;
        float z2 = v2 ? zf[r0 + 128] : 0.f;
        float z3 = v3 ? zf[r0 + 192] : 0.f;

        float y0 = bias1, y1 = bias1, y2 = bias1, y3 = bias1;
        #pragma unroll
        for (int k = 0; k < 64; ++k) {
            float a0 = RL(z0, k);
            float a1 = RL(z1, k);
            float a2 = RL(z2, k);
            float a3 = RL(z3, k);
            y0 = fmaf(a0, w1k[k], y0);
            y1 = fmaf(a1, w1k[k], y1);
            y2 = fmaf(a2, w1k[k], y2);
            y3 = fmaf(a3, w1k[k], y3);
        }
        y0 = fmaxf(y0, 0.f); y1 = fmaxf(y1, 0.f);
        y2 = fmaxf(y2, 0.f); y3 = fmaxf(y3, 0.f);

        float o0 = bias2, o1 = bias2, o2 = bias2, o3 = bias2;
        #pragma unroll
        for (int k = 0; k < 64; ++k) {
            float a0 = RL(y0, k);
            float a1 = RL(y1, k);
            float a2 = RL(y2, k);
            float a3 = RL(y3, k);
            o0 = fmaf(a0, w2k[k], o0);
            o1 = fmaf(a1, w2k[k], o1);
            o2 = fmaf(a2, w2k[k], o2);
            o3 = fmaf(a3, w2k[k], o3);
        }
        float h0 = fmaxf(o0, 0.f);
        float h1 = fmaxf(o1, 0.f);
        float h2 = fmaxf(o2, 0.f);
        float h3 = fmaxf(o3, 0.f);

        // stores: fp32 + bf16 mirror (both coalesced; wave-uniform guards)
        if (v0) {
            zf[r0] = h0;
            __hip_bfloat16 p = __float2bfloat16(h0);
            zb[r0] = *(ushort_t*)&p;
        }
        if (v1) {
            zf[r0 + 64] = h1;
            __hip_bfloat16 p = __float2bfloat16(h1);
            zb[r0 + 64] = *(ushort_t*)&p;
        }
        if (v2) {
            zf[r0 + 128] = h2;
            __hip_bfloat16 p = __float2bfloat16(h2);
            zb[r0 + 128] = *(ushort_t*)&p;
        }
        if (v3) {
            zf[r0 + 192] = h3;
            __hip_bfloat16 p = __float2bfloat16(h3);
            zb[r0 + 192] = *(ushort_t*)&p;
        }

        // stats: lane == feature, plain accumulation (masked for invalid nodes)
        float s0 = v0 ? h0 : 0.f, s1 = v1 ? h1 : 0.f;
        float s2 = v2 ? h2 : 0.f, s3 = v3 ? h3 : 0.f;
        ssum += s0 + s1 + s2 + s3;
        ssq  += s0 * s0 + s1 * s1 + s2 * s2 + s3 * s3;
    }
    // per-wave partials, plain stores (no contention, no atomics)
    partials[(size_t)lane * NWAVE + w]        = ssum;
    partials[(size_t)(64 + lane) * NWAVE + w] = ssq;
}

// reduce per-wave partials -> BN affine (A,C) for this layer's ac slot.
// 64 blocks: block f reduces feature f (sum) and 64+f (sumsq).
__global__ __launch_bounds__(256) void redstats_kernel(
    const float* __restrict__ partials, const float* __restrict__ gammaf,
    const float* __restrict__ betaf, float* __restrict__ ac_out)
{
    __shared__ float s1[256], s2[256];
    int f = blockIdx.x;
    int t = threadIdx.x;
    const float* ph = partials + (size_t)f * NWAVE;
    const float* pq = partials + (size_t)(64 + f) * NWAVE;
    float a = 0.f, b = 0.f;
    for (int i = t; i < NWAVE; i += 256) { a += ph[i]; b += pq[i]; }
    s1[t] = a; s2[t] = b;
    __syncthreads();
    for (int off = 128; off > 0; off >>= 1) {
        if (t < off) { s1[t] += s1[t + off]; s2[t] += s2[t + off]; }
        __syncthreads();
    }
    if (t == 0) {
        const float invN = 1.0f / (float)NN;
        float mu = s1[0] * invN;
        float var = s2[0] * invN - mu * mu;
        if (var < 0.f) var = 0.f;
        float A = gammaf[f] * rsqrtf(var + 1e-5f);
        float C = betaf[f] - mu * A;
        ac_out[f] = A;
        ac_out[64 + f] = C;
    }
}

// pools only: h = A*z + C on the fly; node_pool (+=), gpool run-length atomics.
__global__ __launch_bounds__(256) void pool_kernel(
    const float* __restrict__ z, float* __restrict__ node_pool,
    const int* __restrict__ b32, const float* __restrict__ ac,
    float* __restrict__ gpool, int N, int first)
{
    int wave = (blockIdx.x * 256 + threadIdx.x) >> 6;
    int f = threadIdx.x & 63;
    int n0 = wave * 16;
    if (n0 >= N) return;
    int n1 = min(n0 + 16, N);
    float A = ac[f], C = ac[64 + f];
    float racc = 0.f;
    int cur = b32[n0];
    int n = n0;
    for (; n + 4 <= n1; n += 4) {
        int4 gv = *(const int4*)(b32 + n);
        size_t idx = (size_t)n * 64 + f;
        // 4 independent loads in flight
        float z0 = z[idx];
        float z1 = z[idx + 64];
        float z2 = z[idx + 128];
        float z3 = z[idx + 192];
        float h0 = fmaf(z0, A, C);
        float h1 = fmaf(z1, A, C);
        float h2 = fmaf(z2, A, C);
        float h3 = fmaf(z3, A, C);
        if (first) {
            node_pool[idx]       = h0;
            node_pool[idx + 64]  = h1;
            node_pool[idx + 128] = h2;
            node_pool[idx + 192] = h3;
        } else {
            float p0 = node_pool[idx];
            float p1 = node_pool[idx + 64];
            float p2 = node_pool[idx + 128];
            float p3 = node_pool[idx + 192];
            node_pool[idx]       = p0 + h0;
            node_pool[idx + 64]  = p1 + h1;
            node_pool[idx + 128] = p2 + h2;
            node_pool[idx + 192] = p3 + h3;
        }
        // run-length gpool accumulation, original per-node order
        int gs0 = gv.x, gs1 = gv.y, gs2 = gv.z, gs3 = gv.w;
        if (gs0 != cur) { atomicAdd(&gpool[(size_t)cur * 64 + f], racc); racc = 0.f; cur = gs0; }
        racc += h0;
        if (gs1 != cur) { atomicAdd(&gpool[(size_t)cur * 64 + f], racc); racc = 0.f; cur = gs1; }
        racc += h1;
        if (gs2 != cur) { atomicAdd(&gpool[(size_t)cur * 64 + f], racc); racc = 0.f; cur = gs2; }
        racc += h2;
        if (gs3 != cur) { atomicAdd(&gpool[(size_t)cur * 64 + f], racc); racc = 0.f; cur = gs3; }
        racc += h3;
    }
    for (; n < n1; ++n) {  // tail (unused when 16 | N; kept for safety)
        int g = b32[n];
        if (g != cur) { atomicAdd(&gpool[(size_t)cur * 64 + f], racc); racc = 0.f; cur = g; }
        size_t idx = (size_t)n * 64 + f;
        float hv = fmaf(z[idx], A, C);
        float np = first ? hv : (node_pool[idx] + hv);
        node_pool[idx] = np;
        racc += hv;
    }
    atomicAdd(&gpool[(size_t)cur * 64 + f], racc);
}

__global__ __launch_bounds__(256) void finalize_kernel(
    const float* __restrict__ node_pool, const float* __restrict__ gpool,
    const float* __restrict__ invg, const int* __restrict__ flags,
    void* __restrict__ out, int N)
{
    int i = blockIdx.x * 256 + threadIdx.x;
    int nd = N * 64;
    int total = nd + GG * 64;
    if (i >= total) return;
    float v;
    if (i < nd) v = node_pool[i];
    else { int j = i - nd; v = gpool[j] * invg[j >> 6]; }
    if (flags[0]) ((float*)out)[i] = v;
    else ((__hip_bfloat16*)out)[i] = __float2bfloat16(v);
}

extern "C" void kernel_launch(void* const* d_in, const int* in_sizes, int n_in,
                              void* d_out, int out_size, void* d_ws, size_t ws_size,
                              hipStream_t stream)
{
    constexpr int N = NN, E = EE, G = GG;
    constexpr int ND = N * 64;

    const void* x     = d_in[0];
    const void* W1    = d_in[1];
    const void* b1    = d_in[2];
    const void* W2    = d_in[3];
    const void* b2    = d_in[4];
    const void* gamma = d_in[5];
    const void* beta  = d_in[6];
    const int* ei     = (const int*)d_in[7];
    const int* batw   = (const int*)d_in[8];

    char* p = (char*)d_ws;
    auto alloc = [&](size_t bytes) -> char* {
        char* r = p;
        p += (bytes + 255) & ~(size_t)255;
        return r;
    };
    float*    zbufA     = (float*)alloc((size_t)ND * 4);
    float*    zbufB     = (float*)alloc((size_t)ND * 4);
    float*    node_pool = (float*)alloc((size_t)ND * 4);
    ushort_t* zb        = (ushort_t*)alloc((size_t)ND * 2);
    int*      esrc      = (int*)alloc((size_t)E * 4);
    int*      indptr    = (int*)alloc((size_t)(N + 1) * 4);
    int*      deg       = (int*)alloc((size_t)N * 4);
    int*      part      = (int*)alloc((size_t)N * 4);
    float*    invdeg    = (float*)alloc((size_t)N * 4);
    int*      b32       = (int*)alloc((size_t)N * 4);
    int*      bsum      = (int*)alloc(128 * 4);
    int*      gstart    = (int*)alloc((size_t)(G + 1) * 4);
    float*    invg      = (float*)alloc(G * 4);
    float*    gpool     = (float*)alloc((size_t)G * 64 * 4);
    float*    ac5       = (float*)alloc(5 * 128 * 4);  // slot0 identity, slots1..4 BN_l
    float*    partials  = (float*)alloc((size_t)128 * NWAVE * 4);  // 1.6 MB
    float*    wf        = (float*)alloc(33792 * 4);
    int*      flags     = (int*)alloc(16 * 4);
    int*      histo     = (int*)alloc((size_t)NBK * NHB * 4);
    int*      tot       = (int*)alloc((size_t)NBK * 4);
    int*      bktoff    = (int*)alloc((size_t)(NBK + 1) * 4);
    // pairs aliases node_pool: dead until first pool_kernel; E*8 == ND*4 bytes
    int2*     pairs     = (int2*)node_pool;

    hipMemsetAsync(gpool, 0, (size_t)G * 64 * 4, stream);

    detect_kernel<<<1, 256, 0, stream>>>(
        (const uint_t*)x, (const uint_t*)ei, (const uint_t*)batw, flags);
    cvt_w_kernel<<<132, 256, 0, stream>>>(W1, b1, W2, b2, gamma, beta, flags, wf);
    cvt_x_kernel<<<(ND + 255) / 256, 256, 0, stream>>>(x, flags, zbufA, zb, ND);
    cvt_batch_kernel<<<(N + 255) / 256, 256, 0, stream>>>(batw, flags, b32, gstart, N);
    count_hist_kernel<<<NHB, 256, 0, stream>>>(ei, flags, histo, E);
    blockscan_kernel<<<NBK, NHB, 0, stream>>>(histo, tot);
    bscan_kernel<<<1, 512, 0, stream>>>(tot, bktoff);
    pair_scatter_kernel<<<NHB, 256, 0, stream>>>(ei, flags, histo, bktoff, pairs, E);
    bucket_deg_kernel<<<NBK, 256, 0, stream>>>(pairs, bktoff, deg, N);
    int nb = (N + 1023) / 1024;  // 98
    scan1_kernel<<<nb, 256, 0, stream>>>(deg, part, bsum, N);
    scan2_kernel<<<1, 128, 0, stream>>>(bsum, nb);
    scan3_kernel<<<(N + 255) / 256, 256, 0, stream>>>(part, bsum, deg, indptr, invdeg, N);
    invg_kernel<<<1, 512, 0, stream>>>(gstart, invg, ac5, G);
    csr_fill_kernel<<<NBK, 256, 0, stream>>>(pairs, bktoff, indptr, esrc, N);

    float* zin = zbufA;
    float* zout = zbufB;
    for (int l = 0; l < 4; ++l) {
        agg_kernel<<<(N + 15) / 16, 256, 0, stream>>>(
            zin, zb, indptr, esrc, invdeg, ac5 + l * 128, zout, N);
        mlp_kernel<<<MLPBLOCKS, 256, 0, stream>>>(
            zout, zb, wf + l * 4096, wf + 32768 + l * 64,
            wf + 16384 + l * 4096, wf + 33024 + l * 64,
            partials, N);
        redstats_kernel<<<64, 256, 0, stream>>>(
            partials, wf + 33280 + l * 64, wf + 33536 + l * 64,
            ac5 + (l + 1) * 128);
        pool_kernel<<<(N + 63) / 64, 256, 0, stream>>>(
            zout, node_pool, b32, ac5 + (l + 1) * 128, gpool, N, (l == 0) ? 1 : 0);
        float* tmp = zin; zin = zout; zout = tmp;
    }
    finalize_kernel<<<(ND + G * 64 + 255) / 256, 256, 0, stream>>>(
        node_pool, gpool, invg, flags, d_out, N);
}